// Round 23
// baseline (277.561 us; speedup 1.0000x reference)
//
#include <hip/hip_runtime.h>

#define N_ 200000
#define E_ 6400000
#define F_ 128
#define H_ 16
#define C_ 10
#define B_ 512

#define CSH   15                     // src chunk: 32768 rows = 2 MB of P (L2-resident window)
#define NCH   7                      // ceil(200000/32768)
#define SBSH  10                     // dst superbucket for agg/part2 halves: 1024 nodes
#define NSB   196                    // ceil(200000/1024)
#define NKEY  (NCH * NSB)            // 1372 (agg/gemm/part2 geometry)
#define NSB11 98                     // part1 partition granularity: 2048-node buckets
#define NKEY11 (NCH * NSB11)         // 686 (part1 keys; chunk = 25000/686 ~ 36 edges = 146B >= 2 lines)
#define NT    256                    // partition tiles
#define EPT   25000                  // NT*EPT == E_
#define N1    (N_ + 1)
#define STG2  6144                   // part2 staging cap (half-partition mean 4665, sigma ~68)
#define AGGB  1563                   // ceil(N_*2/256): 2 nodes per thread (agg)
#define G1B   1563                   // ceil(N_/2*4/256): gemm1 pair x quarter
#define QSTR  516                    // quarter block stride in dwords: 32*16 + 4 pad

// ---------- 1. count1: per-tile histogram over 686 (chunk, dst>>11) keys ----------
__global__ __launch_bounds__(1024) void k_count1(const int* __restrict__ row, const int* __restrict__ col,
                                                 int* __restrict__ cnt1) {
    __shared__ int hist[NKEY11];
    int tid = threadIdx.x, tile = blockIdx.x;
    for (int i = tid; i < NKEY11; i += 1024) hist[i] = 0;
    __syncthreads();
    const int* r = row + (size_t)tile * EPT;
    const int* c = col + (size_t)tile * EPT;
    for (int i = tid; i < EPT; i += 1024) {
        int key = (r[i] >> CSH) * NSB11 + (c[i] >> 11);
        atomicAdd(&hist[key], 1);
    }
    __syncthreads();
    for (int i = tid; i < NKEY11; i += 1024) cnt1[(size_t)i * NT + tile] = hist[i];   // key-major
}

// ---------- generic: per-key scan over NT tiles (4/thread), in place + totals ----------
__global__ __launch_bounds__(256) void k_scan_col(int* __restrict__ cnt_mat, int* __restrict__ keyTotal) {
    __shared__ int s[256];
    int k = blockIdx.x, t = threadIdx.x;
    int v[4];
    int seg = 0;
#pragma unroll
    for (int j = 0; j < 4; ++j) {
        int idx = 4 * t + j;
        v[j] = (idx < NT) ? cnt_mat[(size_t)k * NT + idx] : 0;
        seg += v[j];
    }
    s[t] = seg;
    __syncthreads();
    for (int off = 1; off < 256; off <<= 1) {
        int tmp = (t >= off) ? s[t - off] : 0;
        __syncthreads();
        s[t] += tmp;
        __syncthreads();
    }
    if (t == 255) keyTotal[k] = s[255];
    int running = s[t] - seg;
#pragma unroll
    for (int j = 0; j < 4; ++j) {
        int idx = 4 * t + j;
        if (idx < NT) {
            int old = v[j];
            cnt_mat[(size_t)k * NT + idx] = running;
            running += old;
        }
    }
}

// ---------- generic: looped scan of n totals -> start[n+1] ----------
__global__ __launch_bounds__(1024) void k_scan_top(const int* __restrict__ keyTotal, int* __restrict__ keyStart, int n) {
    __shared__ int s[1024];
    __shared__ int base;
    int t = threadIdx.x;
    if (t == 0) base = 0;
    __syncthreads();
    int ntile = (n + 1023) / 1024;
    for (int tile = 0; tile < ntile; ++tile) {
        int idx = tile * 1024 + t;
        int v = (idx < n) ? keyTotal[idx] : 0;
        s[t] = v;
        __syncthreads();
        for (int off = 1; off < 1024; off <<= 1) {
            int tmp = (t >= off) ? s[t - off] : 0;
            __syncthreads();
            s[t] += tmp;
            __syncthreads();
        }
        if (idx < n) keyStart[idx] = base + s[t] - v;
        __syncthreads();
        if (t == 0) base += s[1023];
        __syncthreads();
    }
    if (t == 0) keyStart[n] = base;
}

// ---------- 2. part1: scatter by 686 keys into scratch; word = (dst&2047)<<15 | srcL ----------
__global__ __launch_bounds__(1024) void k_part1(const int* __restrict__ row, const int* __restrict__ col,
                                                const int* __restrict__ cnt1, const int* __restrict__ ks686,
                                                unsigned int* __restrict__ esrc) {
    __shared__ int cur[NKEY11];
    int tid = threadIdx.x, tile = blockIdx.x;
    for (int i = tid; i < NKEY11; i += 1024) cur[i] = cnt1[(size_t)i * NT + tile] + ks686[i];
    __syncthreads();
    const int* r = row + (size_t)tile * EPT;
    const int* c = col + (size_t)tile * EPT;
    for (int i = tid; i < EPT; i += 1024) {
        int src = r[i], dst = c[i];
        int key = (src >> CSH) * NSB11 + (dst >> 11);
        int p = atomicAdd(&cur[key], 1);
        esrc[p] = ((unsigned int)(dst & 2047) << CSH) | (unsigned int)(src & 32767);
    }
}

// ---------- 3. part2 v5: 1372 blocks; block = half of a (c,sb11) partition; u16 sorted output ----------
// LDS = stg(u16) 12.3 KB + cnt 4 KB + aux 2 KB ~= 18.3 KB; 512 threads -> 4 blocks/CU.
__global__ __launch_bounds__(512) void k_part2(const unsigned int* __restrict__ esrc, const int* __restrict__ ks686,
                                               int* __restrict__ ks10, unsigned short* __restrict__ off16,
                                               unsigned short* __restrict__ edges) {
    __shared__ unsigned short stg[STG2]; // 12.3 KB
    __shared__ int cnt[1024];            // 4 KB
    __shared__ int aux[512];             // 2 KB
    int b = blockIdx.x, tid = threadIdx.x;
    int c = b / NSB, rem = b % NSB;      // rem = sb10
    int sb11 = rem >> 1, h = rem & 1;
    int s = ks686[c * NSB11 + sb11], e = ks686[c * NSB11 + sb11 + 1], len = e - s;
    cnt[tid] = 0;
    cnt[tid + 512] = 0;
    __syncthreads();
    // pass 1: histogram of matching half
    for (int i = tid; i < len; i += 512) {
        unsigned int dl = esrc[s + i] >> CSH;          // 11-bit dst_local
        if ((int)(dl >> 10) == h) atomicAdd(&cnt[dl & 1023], 1);
    }
    __syncthreads();
    // exclusive scan of cnt[1024]: 2/thread + block scan over 512
    int base = tid * 2;
    int v0 = cnt[base], v1 = cnt[base + 1];
    int run = v0 + v1;
    aux[tid] = run;
    __syncthreads();
    for (int o = 1; o < 512; o <<= 1) {
        int tmp = (tid >= o) ? aux[tid - o] : 0;
        __syncthreads();
        aux[tid] += tmp;
        __syncthreads();
    }
    int total = aux[511];                              // matches in this half
    int acc = aux[tid] - run;
    int nb = (rem << SBSH) + base;                     // node = sb10*1024 + bin
    cnt[base] = acc;
    if (nb < N_) off16[(size_t)c * N1 + nb] = (unsigned short)acc;
    acc += v0;
    cnt[base + 1] = acc;
    if (nb + 1 < N_) off16[(size_t)c * N1 + nb + 1] = (unsigned short)acc;
    __syncthreads();
    int myStart = s + h * (len - total);               // h=0: s; h=1: s + len0
    if (tid == 0) {
        ks10[b] = myStart;
        if (b == NKEY - 1) ks10[NKEY] = myStart + total;           // == E_
        if (rem == NSB - 1) off16[(size_t)c * N1 + N_] = (unsigned short)total;
    }
    // pass 2: scatter matches into LDS staging at sorted pos, then coalesced u16 flush
    if (total <= STG2) {
        for (int i = tid; i < len; i += 512) {
            unsigned int w = esrc[s + i];
            unsigned int dl = w >> CSH;
            if ((int)(dl >> 10) == h) {
                int pos = atomicAdd(&cnt[dl & 1023], 1);
                stg[pos] = (unsigned short)(w & 32767u);
            }
        }
        __syncthreads();
        for (int i = tid; i < total; i += 512) edges[(size_t)myStart + i] = stg[i];
    } else {   // statistically unreachable (cap ~ mean+21sigma); correct scattered fallback
        for (int i = tid; i < len; i += 512) {
            unsigned int w = esrc[s + i];
            unsigned int dl = w >> CSH;
            if ((int)(dl >> 10) == h) {
                int pos = atomicAdd(&cnt[dl & 1023], 1);
                edges[(size_t)myStart + pos] = (unsigned short)(w & 32767u);
            }
        }
    }
}

// ---------- 4. GEMM1 v4: pair x quarter with INTERLEAVED k-split for full-line x coalescing ----------
__global__ __launch_bounds__(256) void k_gemm1s(const float* __restrict__ x, const float* __restrict__ W1,
                                                const unsigned short* __restrict__ off16, const int* __restrict__ ks1g,
                                                float* __restrict__ dis, float* __restrict__ P) {
    __shared__ float wsh[4 * QSTR];      // 8.3 KB
    __shared__ int ks[NKEY + 1];         // 5.5 KB
    for (int i = threadIdx.x; i < F_ * H_; i += 256) {
        int r = i >> 4, h = i & 15;
        int qq = (r >> 2) & 3, jj = r >> 4, mm = r & 3;   // r = 16*jj + 4*qq + mm
        wsh[qq * QSTR + (jj * 4 + mm) * 16 + h] = W1[i];
    }
    for (int i = threadIdx.x; i <= NKEY; i += 256) ks[i] = ks1g[i];
    __syncthreads();
    int t = blockIdx.x * 256 + threadIdx.x;
    int p = t >> 2, q = t & 3;
    int n0 = p * 2;
    if (n0 >= N_) return;
    int sb00 = n0 >> SBSH, sb01 = (n0 + 1) >> SBSH, sbE = (n0 + 2) >> SBSH;
    int deg0 = 0, deg1 = 0;
    for (int c = q; c < NCH; c += 4) {
        const unsigned short* ob = off16 + (size_t)c * N1 + n0;
        ushort2 o2 = *(const ushort2*)ob;
        unsigned short oE = ob[2];
        deg0 += (ks[c * NSB + sb01] + o2.y) - (ks[c * NSB + sb00] + o2.x);
        deg1 += (ks[c * NSB + sbE] + oE) - (ks[c * NSB + sb01] + o2.y);
    }
    deg0 += __shfl_xor(deg0, 1); deg0 += __shfl_xor(deg0, 2);
    deg1 += __shfl_xor(deg1, 1); deg1 += __shfl_xor(deg1, 2);
    float dn0 = rsqrtf(1.0f + (float)deg0);
    float dn1 = rsqrtf(1.0f + (float)deg1);
    if (q == 0) dis[n0] = dn0;
    if (q == 1) dis[n0 + 1] = dn1;
    const float4* xr0 = (const float4*)(x + (size_t)n0 * F_);
    const float4* xr1 = (const float4*)(x + (size_t)(n0 + 1) * F_);
    const float4* wq = (const float4*)(wsh + q * QSTR);
    float4 a0q0 = {0,0,0,0}, a0q1 = {0,0,0,0}, a0q2 = {0,0,0,0}, a0q3 = {0,0,0,0};
    float4 a1q0 = {0,0,0,0}, a1q1 = {0,0,0,0}, a1q2 = {0,0,0,0}, a1q3 = {0,0,0,0};
#define KSTEP(RL, XS0, XS1)                                                        \
    {                                                                              \
        float4 w0 = wq[(RL) * 4 + 0], w1 = wq[(RL) * 4 + 1];                       \
        float4 w2 = wq[(RL) * 4 + 2], w3 = wq[(RL) * 4 + 3];                       \
        a0q0.x += (XS0) * w0.x; a0q0.y += (XS0) * w0.y; a0q0.z += (XS0) * w0.z; a0q0.w += (XS0) * w0.w; \
        a0q1.x += (XS0) * w1.x; a0q1.y += (XS0) * w1.y; a0q1.z += (XS0) * w1.z; a0q1.w += (XS0) * w1.w; \
        a0q2.x += (XS0) * w2.x; a0q2.y += (XS0) * w2.y; a0q2.z += (XS0) * w2.z; a0q2.w += (XS0) * w2.w; \
        a0q3.x += (XS0) * w3.x; a0q3.y += (XS0) * w3.y; a0q3.z += (XS0) * w3.z; a0q3.w += (XS0) * w3.w; \
        a1q0.x += (XS1) * w0.x; a1q0.y += (XS1) * w0.y; a1q0.z += (XS1) * w0.z; a1q0.w += (XS1) * w0.w; \
        a1q1.x += (XS1) * w1.x; a1q1.y += (XS1) * w1.y; a1q1.z += (XS1) * w1.z; a1q1.w += (XS1) * w1.w; \
        a1q2.x += (XS1) * w2.x; a1q2.y += (XS1) * w2.y; a1q2.z += (XS1) * w2.z; a1q2.w += (XS1) * w2.w; \
        a1q3.x += (XS1) * w3.x; a1q3.y += (XS1) * w3.y; a1q3.z += (XS1) * w3.z; a1q3.w += (XS1) * w3.w; \
    }
#pragma unroll
    for (int j = 0; j < 8; ++j) {
        float4 xa = xr0[j * 4 + q];     // k = 16j + 4q + {0..3}: 4 q-lanes cover one 64B line
        float4 xb = xr1[j * 4 + q];
        int rb = j * 4;
        KSTEP(rb + 0, xa.x, xb.x)
        KSTEP(rb + 1, xa.y, xb.y)
        KSTEP(rb + 2, xa.z, xb.z)
        KSTEP(rb + 3, xa.w, xb.w)
    }
#undef KSTEP
#define RED(F)                                                                     \
    F.x += __shfl_xor(F.x, 1); F.y += __shfl_xor(F.y, 1); F.z += __shfl_xor(F.z, 1); F.w += __shfl_xor(F.w, 1); \
    F.x += __shfl_xor(F.x, 2); F.y += __shfl_xor(F.y, 2); F.z += __shfl_xor(F.z, 2); F.w += __shfl_xor(F.w, 2);
    RED(a0q0) RED(a0q1) RED(a0q2) RED(a0q3)
    RED(a1q0) RED(a1q1) RED(a1q2) RED(a1q3)
#undef RED
    float4 s0 = (q == 0) ? a0q0 : (q == 1) ? a0q1 : (q == 2) ? a0q2 : a0q3;
    float4 s1 = (q == 0) ? a1q0 : (q == 1) ? a1q1 : (q == 2) ? a1q2 : a1q3;
    float4* P4 = (float4*)P;
    float4 o0, o1;
    o0.x = s0.x * dn0; o0.y = s0.y * dn0; o0.z = s0.z * dn0; o0.w = s0.w * dn0;
    o1.x = s1.x * dn1; o1.y = s1.y * dn1; o1.z = s1.z * dn1; o1.w = s1.w * dn1;
    P4[(size_t)n0 * 4 + q] = o0;
    P4[(size_t)(n0 + 1) * 4 + q] = o1;
}

// ---------- 6. GEMM2: P = dis*(hin@W2)  (hin already ReLU'd by agg<1>) ----------
__global__ __launch_bounds__(256) void k_gemm2s(const float* __restrict__ hin, const float* __restrict__ W2,
                                                const float* __restrict__ dis, float* __restrict__ P) {
    __shared__ float w[H_ * H_];
    if (threadIdx.x < H_ * H_) w[threadIdx.x] = W2[threadIdx.x];
    __syncthreads();
    int n = blockIdx.x * 256 + threadIdx.x;
    if (n >= N_) return;
    float hv[H_];
    const float4* hr = reinterpret_cast<const float4*>(hin + (size_t)n * H_);
#pragma unroll
    for (int q = 0; q < 4; ++q) {
        float4 v = hr[q];
        hv[q * 4 + 0] = v.x; hv[q * 4 + 1] = v.y; hv[q * 4 + 2] = v.z; hv[q * 4 + 3] = v.w;
    }
    float acc[H_];
#pragma unroll
    for (int h = 0; h < H_; ++h) acc[h] = 0.f;
#pragma unroll
    for (int k = 0; k < H_; ++k)
#pragma unroll
        for (int h = 0; h < H_; ++h) acc[h] += hv[k] * w[k * H_ + h];
    float dn = dis[n];
    float* o = P + (size_t)n * H_;
#pragma unroll
    for (int h = 0; h < H_; h += 4)
        *(float4*)(o + h) = make_float4(acc[h] * dn, acc[h + 1] * dn, acc[h + 2] * dn, acc[h + 3] * dn);
}

// ---------- 5/7. CSR aggregation: 2 adjacent nodes per thread; u16 edges (chunk implicit) ----------
template <int RELU>
__global__ __launch_bounds__(256) void k_agg(const float4* __restrict__ P4, const unsigned short* __restrict__ csr16,
                                             const unsigned short* __restrict__ off16, const int* __restrict__ ks1g,
                                             const float* __restrict__ dis, const float* __restrict__ bias,
                                             float4* __restrict__ Q4) {
    __shared__ int ks[NKEY + 1];
    for (int i = threadIdx.x; i <= NKEY; i += 256) ks[i] = ks1g[i];
    __syncthreads();
    int g = threadIdx.x >> 2, hq = threadIdx.x & 3;
    int n0 = blockIdx.x * 128 + g * 2;             // node pair n0, n0+1 (N_ even)
    if (n0 >= N_) return;
    int sb  = n0 >> SBSH;
    int sbE = (n0 + 2) >> SBSH;
    float4 acc0 = {0,0,0,0}, acc1 = {0,0,0,0};
    const unsigned short* ob = off16 + n0;
    ushort2 o2 = *(const ushort2*)ob;
    unsigned short oE = ob[2];
#pragma unroll
    for (int c = 0; c < NCH; ++c) {
        int bs = ks[c * NSB + sb];
        int be = ks[c * NSB + sbE];
        int s0 = bs + o2.x;
        int s1 = bs + o2.y;
        int e1 = be + oE;
        if (c + 1 < NCH) {
            const unsigned short* obn = off16 + (size_t)(c + 1) * N1 + n0;
            o2 = *(const ushort2*)obn;
            oE = obn[2];
        }
        const float4* Pc = P4 + ((size_t)c << CSH) * 4 + hq;   // chunk base (+hq)
#pragma unroll 4
        for (int p = s0; p < e1; ++p) {
            float4 v = Pc[(size_t)csr16[p] * 4];
            float w0 = (p < s1) ? 1.f : 0.f;
            float w1 = 1.f - w0;
            acc0.x += w0 * v.x; acc0.y += w0 * v.y; acc0.z += w0 * v.z; acc0.w += w0 * v.w;
            acc1.x += w1 * v.x; acc1.y += w1 * v.y; acc1.z += w1 * v.z; acc1.w += w1 * v.w;
        }
    }
    float2 d2 = *(const float2*)(dis + n0);
    float4 b4 = ((const float4*)bias)[hq];
#define FINISH(ACC, K, DN)                                            \
    {                                                                 \
        float4 self = P4[(size_t)(n0 + K) * 4 + hq];                  \
        float4 v;                                                     \
        v.x = (DN) * (ACC.x + self.x) + b4.x;                         \
        v.y = (DN) * (ACC.y + self.y) + b4.y;                         \
        v.z = (DN) * (ACC.z + self.z) + b4.z;                         \
        v.w = (DN) * (ACC.w + self.w) + b4.w;                         \
        if (RELU) {                                                   \
            v.x = fmaxf(v.x, 0.f); v.y = fmaxf(v.y, 0.f);             \
            v.z = fmaxf(v.z, 0.f); v.w = fmaxf(v.w, 0.f);             \
        }                                                             \
        Q4[(size_t)(n0 + K) * 4 + hq] = v;                            \
    }
    FINISH(acc0, 0, d2.x)
    FINISH(acc1, 1, d2.y)
#undef FINISH
}

// ---------- 8. pool + fc ----------
__global__ __launch_bounds__(256) void k_pool_fc(const float* __restrict__ h2, const int* __restrict__ batch,
                                                 const float* __restrict__ Wfc, const float* __restrict__ bfc,
                                                 float* __restrict__ out) {
    int b = blockIdx.x;
    int lo = 0, hi = N_;
    while (lo < hi) { int m = (lo + hi) >> 1; if (batch[m] < b) lo = m + 1; else hi = m; }
    int start = lo;
    lo = start; hi = N_;
    while (lo < hi) { int m = (lo + hi) >> 1; if (batch[m] < b + 1) lo = m + 1; else hi = m; }
    int end = lo;

    int t = threadIdx.x;
    int h = t & 15, q = t >> 4;
    float acc = 0.f;
    for (int n = start + q; n < end; n += 16) acc += h2[(size_t)n * H_ + h];
    acc += __shfl_xor(acc, 16);
    acc += __shfl_xor(acc, 32);

    __shared__ float part[4][H_];
    __shared__ float pooled[H_];
    if ((t & 63) < 16) part[t >> 6][h] = acc;
    __syncthreads();
    if (t < H_) {
        float s2 = part[0][t] + part[1][t] + part[2][t] + part[3][t];
        pooled[t] = s2 / fmaxf((float)(end - start), 1.0f);
    }
    __syncthreads();
    if (t < C_) {
        float o = bfc[t];
#pragma unroll
        for (int hh = 0; hh < H_; ++hh) o += pooled[hh] * Wfc[hh * C_ + t];
        out[b * C_ + t] = o;
    }
}

extern "C" void kernel_launch(void* const* d_in, const int* in_sizes, int n_in,
                              void* d_out, int out_size, void* d_ws, size_t ws_size,
                              hipStream_t stream) {
    const float* x    = (const float*)d_in[0];
    const int*   ei   = (const int*)d_in[1];
    const int*   batch= (const int*)d_in[2];
    const float* W1   = (const float*)d_in[3];
    const float* b1   = (const float*)d_in[4];
    const float* W2   = (const float*)d_in[5];
    const float* b2   = (const float*)d_in[6];
    const float* Wfc  = (const float*)d_in[7];
    const float* bfc  = (const float*)d_in[8];
    float* out = (float*)d_out;

    const int* row = ei;          // sources
    const int* col = ei + E_;     // destinations

    size_t off = 0;
    auto alloc = [&](size_t bytes) -> void* {
        void* p = (char*)d_ws + off;
        off += (bytes + 255) & ~(size_t)255;
        return p;
    };
    // union: cnt1 (686*256*4 = 702 KB) dead after k_part1; off16 (7*N1*2 = 2.8 MB) written in k_part2
    char*           U        = (char*)alloc((size_t)NCH * N1 * 2);
    int*            cnt1     = (int*)U;
    unsigned short* off16    = (unsigned short*)U;
    int*            keyTotal = (int*)alloc((size_t)NKEY11 * 4);
    int*            ks686    = (int*)alloc((size_t)(NKEY11 + 1) * 4);
    int*            ks10     = (int*)alloc((size_t)(NKEY + 1) * 4);
    unsigned short* edges    = (unsigned short*)alloc((size_t)E_ * 2);   // 12.8 MB (final sorted CSR, u16)
    float*          dis      = (float*)alloc((size_t)N_ * 4);            // 0.8 MB
    float*          P        = (float*)alloc((size_t)N_ * H_ * 4);       // 12.8 MB
    float*          Q        = (float*)alloc((size_t)N_ * H_ * 4);       // 12.8 MB, contiguous after P
    // esrc (E_ words = 25.6 MB) aliases P∪Q: written by part1, consumed by part2, dead before gemm1 writes P.
    unsigned int*   esrc     = (unsigned int*)P;
    (void)ws_size; (void)in_sizes; (void)n_in; (void)out_size;

    const int gridN = (N_ + 255) / 256;

    // partition by 686 (chunk, dst>>11) keys (coarse -> full-line scatter chunks)
    k_count1  <<<NT, 1024, 0, stream>>>(row, col, cnt1);
    k_scan_col<<<NKEY11, 256, 0, stream>>>(cnt1, keyTotal);
    k_scan_top<<<1, 1024, 0, stream>>>(keyTotal, ks686, NKEY11);
    k_part1   <<<NT, 1024, 0, stream>>>(row, col, cnt1, ks686, esrc);
    // fine sort: 1372 blocks, each sorts one half-partition (dst bit 10 filter); emits ks10 + off16 + u16 edges
    k_part2   <<<NKEY, 512, 0, stream>>>(esrc, ks686, ks10, off16, edges);

    // conv1 (dis fused into gemm1; pair x interleaved-quarter decomposition)
    k_gemm1s<<<G1B, 256, 0, stream>>>(x, W1, off16, ks10, dis, P);
    k_agg<1><<<AGGB, 256, 0, stream>>>((const float4*)P, edges, off16, ks10, dis, b1, (float4*)Q);
    // conv2
    k_gemm2s<<<gridN, 256, 0, stream>>>(Q, W2, dis, P);
    k_agg<0><<<AGGB, 256, 0, stream>>>((const float4*)P, edges, off16, ks10, dis, b2, (float4*)Q);

    k_pool_fc<<<B_, 256, 0, stream>>>(Q, batch, Wfc, bfc, out);
}

// Round 24
// 264.459 us; speedup vs baseline: 1.0495x; 1.0495x over previous
//
#include <hip/hip_runtime.h>

#define N_ 200000
#define E_ 6400000
#define F_ 128
#define H_ 16
#define C_ 10
#define B_ 512

#define CSH   15                     // src chunk: 32768 rows = 2 MB of P (L2-resident window)
#define NCH   7                      // ceil(200000/32768)
#define SBSH  10                     // dst superbucket for agg/part2 halves: 1024 nodes
#define NSB   196                    // ceil(200000/1024)
#define NKEY  (NCH * NSB)            // 1372 (agg/gemm/part2 geometry)
#define NSB11 98                     // part1 partition granularity: 2048-node buckets
#define NKEY11 (NCH * NSB11)         // 686 (part1 keys; chunk = 25000/686 ~ 36 edges = 146B >= 2 lines)
#define NT    256                    // partition tiles
#define EPT   25000                  // NT*EPT == E_
#define N1    (N_ + 1)
#define STG2  6144                   // part2 staging cap (half-partition mean 4665, sigma ~68)
#define AGGB  1563                   // ceil(N_*2/256): 2 nodes per thread (agg)
#define G1B   1563                   // ceil(N_/2*4/256): gemm1 pair x quarter
#define QSTR  516                    // quarter block stride in dwords: 32*16 + 4 pad

// ---------- 1. count1: per-tile histogram over 686 (chunk, dst>>11) keys ----------
__global__ __launch_bounds__(1024) void k_count1(const int* __restrict__ row, const int* __restrict__ col,
                                                 int* __restrict__ cnt1) {
    __shared__ int hist[NKEY11];
    int tid = threadIdx.x, tile = blockIdx.x;
    for (int i = tid; i < NKEY11; i += 1024) hist[i] = 0;
    __syncthreads();
    const int* r = row + (size_t)tile * EPT;
    const int* c = col + (size_t)tile * EPT;
    for (int i = tid; i < EPT; i += 1024) {
        int key = (r[i] >> CSH) * NSB11 + (c[i] >> 11);
        atomicAdd(&hist[key], 1);
    }
    __syncthreads();
    for (int i = tid; i < NKEY11; i += 1024) cnt1[(size_t)i * NT + tile] = hist[i];   // key-major
}

// ---------- generic: per-key scan over NT tiles (4/thread), in place + totals ----------
__global__ __launch_bounds__(256) void k_scan_col(int* __restrict__ cnt_mat, int* __restrict__ keyTotal) {
    __shared__ int s[256];
    int k = blockIdx.x, t = threadIdx.x;
    int v[4];
    int seg = 0;
#pragma unroll
    for (int j = 0; j < 4; ++j) {
        int idx = 4 * t + j;
        v[j] = (idx < NT) ? cnt_mat[(size_t)k * NT + idx] : 0;
        seg += v[j];
    }
    s[t] = seg;
    __syncthreads();
    for (int off = 1; off < 256; off <<= 1) {
        int tmp = (t >= off) ? s[t - off] : 0;
        __syncthreads();
        s[t] += tmp;
        __syncthreads();
    }
    if (t == 255) keyTotal[k] = s[255];
    int running = s[t] - seg;
#pragma unroll
    for (int j = 0; j < 4; ++j) {
        int idx = 4 * t + j;
        if (idx < NT) {
            int old = v[j];
            cnt_mat[(size_t)k * NT + idx] = running;
            running += old;
        }
    }
}

// ---------- generic: looped scan of n totals -> start[n+1] ----------
__global__ __launch_bounds__(1024) void k_scan_top(const int* __restrict__ keyTotal, int* __restrict__ keyStart, int n) {
    __shared__ int s[1024];
    __shared__ int base;
    int t = threadIdx.x;
    if (t == 0) base = 0;
    __syncthreads();
    int ntile = (n + 1023) / 1024;
    for (int tile = 0; tile < ntile; ++tile) {
        int idx = tile * 1024 + t;
        int v = (idx < n) ? keyTotal[idx] : 0;
        s[t] = v;
        __syncthreads();
        for (int off = 1; off < 1024; off <<= 1) {
            int tmp = (t >= off) ? s[t - off] : 0;
            __syncthreads();
            s[t] += tmp;
            __syncthreads();
        }
        if (idx < n) keyStart[idx] = base + s[t] - v;
        __syncthreads();
        if (t == 0) base += s[1023];
        __syncthreads();
    }
    if (t == 0) keyStart[n] = base;
}

// ---------- 2. part1: scatter by 686 keys into scratch; word = (dst&2047)<<15 | srcL ----------
__global__ __launch_bounds__(1024) void k_part1(const int* __restrict__ row, const int* __restrict__ col,
                                                const int* __restrict__ cnt1, const int* __restrict__ ks686,
                                                unsigned int* __restrict__ esrc) {
    __shared__ int cur[NKEY11];
    int tid = threadIdx.x, tile = blockIdx.x;
    for (int i = tid; i < NKEY11; i += 1024) cur[i] = cnt1[(size_t)i * NT + tile] + ks686[i];
    __syncthreads();
    const int* r = row + (size_t)tile * EPT;
    const int* c = col + (size_t)tile * EPT;
    for (int i = tid; i < EPT; i += 1024) {
        int src = r[i], dst = c[i];
        int key = (src >> CSH) * NSB11 + (dst >> 11);
        int p = atomicAdd(&cur[key], 1);
        esrc[p] = ((unsigned int)(dst & 2047) << CSH) | (unsigned int)(src & 32767);
    }
}

// ---------- 3. part2: 1372 blocks; block = half of a (c,sb11) partition (filter dst bit 10) ----------
__global__ __launch_bounds__(512) void k_part2(const unsigned int* __restrict__ esrc, const int* __restrict__ ks686,
                                               int* __restrict__ ks10, unsigned short* __restrict__ off16,
                                               unsigned int* __restrict__ edges) {
    __shared__ unsigned int stg[STG2];   // 24.6 KB
    __shared__ int cnt[1024];            // 4 KB
    __shared__ int aux[512];             // 2 KB
    int b = blockIdx.x, tid = threadIdx.x;
    int c = b / NSB, rem = b % NSB;      // rem = sb10
    int sb11 = rem >> 1, h = rem & 1;
    int s = ks686[c * NSB11 + sb11], e = ks686[c * NSB11 + sb11 + 1], len = e - s;
    cnt[tid] = 0;
    cnt[tid + 512] = 0;
    __syncthreads();
    // pass 1: histogram of matching half
    for (int i = tid; i < len; i += 512) {
        unsigned int dl = esrc[s + i] >> CSH;          // 11-bit dst_local
        if ((int)(dl >> 10) == h) atomicAdd(&cnt[dl & 1023], 1);
    }
    __syncthreads();
    // exclusive scan of cnt[1024]: 2/thread + block scan over 512
    int base = tid * 2;
    int v0 = cnt[base], v1 = cnt[base + 1];
    int run = v0 + v1;
    aux[tid] = run;
    __syncthreads();
    for (int o = 1; o < 512; o <<= 1) {
        int tmp = (tid >= o) ? aux[tid - o] : 0;
        __syncthreads();
        aux[tid] += tmp;
        __syncthreads();
    }
    int total = aux[511];                              // matches in this half
    int acc = aux[tid] - run;
    int nb = (rem << SBSH) + base;                     // node = sb10*1024 + bin
    cnt[base] = acc;
    if (nb < N_) off16[(size_t)c * N1 + nb] = (unsigned short)acc;
    acc += v0;
    cnt[base + 1] = acc;
    if (nb + 1 < N_) off16[(size_t)c * N1 + nb + 1] = (unsigned short)acc;
    __syncthreads();
    int myStart = s + h * (len - total);               // h=0: s; h=1: s + len0
    if (tid == 0) {
        ks10[b] = myStart;
        if (b == NKEY - 1) ks10[NKEY] = myStart + total;           // == E_
        if (rem == NSB - 1) off16[(size_t)c * N1 + N_] = (unsigned short)total;
    }
    // pass 2: scatter matches into LDS staging at sorted pos, then coalesced flush
    if (total <= STG2) {
        for (int i = tid; i < len; i += 512) {
            unsigned int w = esrc[s + i];
            unsigned int dl = w >> CSH;
            if ((int)(dl >> 10) == h) {
                int pos = atomicAdd(&cnt[dl & 1023], 1);
                stg[pos] = ((unsigned int)c << CSH) | (w & 32767u);
            }
        }
        __syncthreads();
        for (int i = tid; i < total; i += 512) edges[myStart + i] = stg[i];
    } else {   // statistically unreachable (cap ~ mean+21sigma); correct scattered fallback
        for (int i = tid; i < len; i += 512) {
            unsigned int w = esrc[s + i];
            unsigned int dl = w >> CSH;
            if ((int)(dl >> 10) == h) {
                int pos = atomicAdd(&cnt[dl & 1023], 1);
                edges[myStart + pos] = ((unsigned int)c << CSH) | (w & 32767u);
            }
        }
    }
}

// ---------- 4. GEMM1: pair x quarter with INTERLEAVED k-split for full-line x coalescing ----------
__global__ __launch_bounds__(256) void k_gemm1s(const float* __restrict__ x, const float* __restrict__ W1,
                                                const unsigned short* __restrict__ off16, const int* __restrict__ ks1g,
                                                float* __restrict__ dis, float* __restrict__ P) {
    __shared__ float wsh[4 * QSTR];      // 8.3 KB
    __shared__ int ks[NKEY + 1];         // 5.5 KB
    for (int i = threadIdx.x; i < F_ * H_; i += 256) {
        int r = i >> 4, h = i & 15;
        int qq = (r >> 2) & 3, jj = r >> 4, mm = r & 3;   // r = 16*jj + 4*qq + mm
        wsh[qq * QSTR + (jj * 4 + mm) * 16 + h] = W1[i];
    }
    for (int i = threadIdx.x; i <= NKEY; i += 256) ks[i] = ks1g[i];
    __syncthreads();
    int t = blockIdx.x * 256 + threadIdx.x;
    int p = t >> 2, q = t & 3;
    int n0 = p * 2;
    if (n0 >= N_) return;
    int sb00 = n0 >> SBSH, sb01 = (n0 + 1) >> SBSH, sbE = (n0 + 2) >> SBSH;
    int deg0 = 0, deg1 = 0;
    for (int c = q; c < NCH; c += 4) {
        const unsigned short* ob = off16 + (size_t)c * N1 + n0;
        ushort2 o2 = *(const ushort2*)ob;
        unsigned short oE = ob[2];
        deg0 += (ks[c * NSB + sb01] + o2.y) - (ks[c * NSB + sb00] + o2.x);
        deg1 += (ks[c * NSB + sbE] + oE) - (ks[c * NSB + sb01] + o2.y);
    }
    deg0 += __shfl_xor(deg0, 1); deg0 += __shfl_xor(deg0, 2);
    deg1 += __shfl_xor(deg1, 1); deg1 += __shfl_xor(deg1, 2);
    float dn0 = rsqrtf(1.0f + (float)deg0);
    float dn1 = rsqrtf(1.0f + (float)deg1);
    if (q == 0) dis[n0] = dn0;
    if (q == 1) dis[n0 + 1] = dn1;
    const float4* xr0 = (const float4*)(x + (size_t)n0 * F_);
    const float4* xr1 = (const float4*)(x + (size_t)(n0 + 1) * F_);
    const float4* wq = (const float4*)(wsh + q * QSTR);
    float4 a0q0 = {0,0,0,0}, a0q1 = {0,0,0,0}, a0q2 = {0,0,0,0}, a0q3 = {0,0,0,0};
    float4 a1q0 = {0,0,0,0}, a1q1 = {0,0,0,0}, a1q2 = {0,0,0,0}, a1q3 = {0,0,0,0};
#define KSTEP(RL, XS0, XS1)                                                        \
    {                                                                              \
        float4 w0 = wq[(RL) * 4 + 0], w1 = wq[(RL) * 4 + 1];                       \
        float4 w2 = wq[(RL) * 4 + 2], w3 = wq[(RL) * 4 + 3];                       \
        a0q0.x += (XS0) * w0.x; a0q0.y += (XS0) * w0.y; a0q0.z += (XS0) * w0.z; a0q0.w += (XS0) * w0.w; \
        a0q1.x += (XS0) * w1.x; a0q1.y += (XS0) * w1.y; a0q1.z += (XS0) * w1.z; a0q1.w += (XS0) * w1.w; \
        a0q2.x += (XS0) * w2.x; a0q2.y += (XS0) * w2.y; a0q2.z += (XS0) * w2.z; a0q2.w += (XS0) * w2.w; \
        a0q3.x += (XS0) * w3.x; a0q3.y += (XS0) * w3.y; a0q3.z += (XS0) * w3.z; a0q3.w += (XS0) * w3.w; \
        a1q0.x += (XS1) * w0.x; a1q0.y += (XS1) * w0.y; a1q0.z += (XS1) * w0.z; a1q0.w += (XS1) * w0.w; \
        a1q1.x += (XS1) * w1.x; a1q1.y += (XS1) * w1.y; a1q1.z += (XS1) * w1.z; a1q1.w += (XS1) * w1.w; \
        a1q2.x += (XS1) * w2.x; a1q2.y += (XS1) * w2.y; a1q2.z += (XS1) * w2.z; a1q2.w += (XS1) * w2.w; \
        a1q3.x += (XS1) * w3.x; a1q3.y += (XS1) * w3.y; a1q3.z += (XS1) * w3.z; a1q3.w += (XS1) * w3.w; \
    }
#pragma unroll
    for (int j = 0; j < 8; ++j) {
        float4 xa = xr0[j * 4 + q];     // k = 16j + 4q + {0..3}: 4 q-lanes cover one 64B line
        float4 xb = xr1[j * 4 + q];
        int rb = j * 4;
        KSTEP(rb + 0, xa.x, xb.x)
        KSTEP(rb + 1, xa.y, xb.y)
        KSTEP(rb + 2, xa.z, xb.z)
        KSTEP(rb + 3, xa.w, xb.w)
    }
#undef KSTEP
#define RED(F)                                                                     \
    F.x += __shfl_xor(F.x, 1); F.y += __shfl_xor(F.y, 1); F.z += __shfl_xor(F.z, 1); F.w += __shfl_xor(F.w, 1); \
    F.x += __shfl_xor(F.x, 2); F.y += __shfl_xor(F.y, 2); F.z += __shfl_xor(F.z, 2); F.w += __shfl_xor(F.w, 2);
    RED(a0q0) RED(a0q1) RED(a0q2) RED(a0q3)
    RED(a1q0) RED(a1q1) RED(a1q2) RED(a1q3)
#undef RED
    float4 s0 = (q == 0) ? a0q0 : (q == 1) ? a0q1 : (q == 2) ? a0q2 : a0q3;
    float4 s1 = (q == 0) ? a1q0 : (q == 1) ? a1q1 : (q == 2) ? a1q2 : a1q3;
    float4* P4 = (float4*)P;
    float4 o0, o1;
    o0.x = s0.x * dn0; o0.y = s0.y * dn0; o0.z = s0.z * dn0; o0.w = s0.w * dn0;
    o1.x = s1.x * dn1; o1.y = s1.y * dn1; o1.z = s1.z * dn1; o1.w = s1.w * dn1;
    P4[(size_t)n0 * 4 + q] = o0;
    P4[(size_t)(n0 + 1) * 4 + q] = o1;
}

// ---------- 6. GEMM2: P = dis*(hin@W2)  (hin already ReLU'd by agg<1>) ----------
__global__ __launch_bounds__(256) void k_gemm2s(const float* __restrict__ hin, const float* __restrict__ W2,
                                                const float* __restrict__ dis, float* __restrict__ P) {
    __shared__ float w[H_ * H_];
    if (threadIdx.x < H_ * H_) w[threadIdx.x] = W2[threadIdx.x];
    __syncthreads();
    int n = blockIdx.x * 256 + threadIdx.x;
    if (n >= N_) return;
    float hv[H_];
    const float4* hr = reinterpret_cast<const float4*>(hin + (size_t)n * H_);
#pragma unroll
    for (int q = 0; q < 4; ++q) {
        float4 v = hr[q];
        hv[q * 4 + 0] = v.x; hv[q * 4 + 1] = v.y; hv[q * 4 + 2] = v.z; hv[q * 4 + 3] = v.w;
    }
    float acc[H_];
#pragma unroll
    for (int h = 0; h < H_; ++h) acc[h] = 0.f;
#pragma unroll
    for (int k = 0; k < H_; ++k)
#pragma unroll
        for (int h = 0; h < H_; ++h) acc[h] += hv[k] * w[k * H_ + h];
    float dn = dis[n];
    float* o = P + (size_t)n * H_;
#pragma unroll
    for (int h = 0; h < H_; h += 4)
        *(float4*)(o + h) = make_float4(acc[h] * dn, acc[h + 1] * dn, acc[h + 2] * dn, acc[h + 3] * dn);
}

// ---------- 5/7. CSR aggregation: 2 adjacent nodes per thread, flat per-chunk range ----------
template <int RELU>
__global__ __launch_bounds__(256) void k_agg(const float4* __restrict__ P4, const unsigned int* __restrict__ csr,
                                             const unsigned short* __restrict__ off16, const int* __restrict__ ks1g,
                                             const float* __restrict__ dis, const float* __restrict__ bias,
                                             float4* __restrict__ Q4) {
    __shared__ int ks[NKEY + 1];
    for (int i = threadIdx.x; i <= NKEY; i += 256) ks[i] = ks1g[i];
    __syncthreads();
    int g = threadIdx.x >> 2, hq = threadIdx.x & 3;
    int n0 = blockIdx.x * 128 + g * 2;             // node pair n0, n0+1 (N_ even)
    if (n0 >= N_) return;
    int sb  = n0 >> SBSH;
    int sbE = (n0 + 2) >> SBSH;
    float4 acc0 = {0,0,0,0}, acc1 = {0,0,0,0};
    const unsigned short* ob = off16 + n0;
    ushort2 o2 = *(const ushort2*)ob;
    unsigned short oE = ob[2];
#pragma unroll
    for (int c = 0; c < NCH; ++c) {
        int bs = ks[c * NSB + sb];
        int be = ks[c * NSB + sbE];
        int s0 = bs + o2.x;
        int s1 = bs + o2.y;
        int e1 = be + oE;
        if (c + 1 < NCH) {
            const unsigned short* obn = off16 + (size_t)(c + 1) * N1 + n0;
            o2 = *(const ushort2*)obn;
            oE = obn[2];
        }
#pragma unroll 4
        for (int p = s0; p < e1; ++p) {
            float4 v = P4[(size_t)csr[p] * 4 + hq];
            float w0 = (p < s1) ? 1.f : 0.f;
            float w1 = 1.f - w0;
            acc0.x += w0 * v.x; acc0.y += w0 * v.y; acc0.z += w0 * v.z; acc0.w += w0 * v.w;
            acc1.x += w1 * v.x; acc1.y += w1 * v.y; acc1.z += w1 * v.z; acc1.w += w1 * v.w;
        }
    }
    float2 d2 = *(const float2*)(dis + n0);
    float4 b4 = ((const float4*)bias)[hq];
#define FINISH(ACC, K, DN)                                            \
    {                                                                 \
        float4 self = P4[(size_t)(n0 + K) * 4 + hq];                  \
        float4 v;                                                     \
        v.x = (DN) * (ACC.x + self.x) + b4.x;                         \
        v.y = (DN) * (ACC.y + self.y) + b4.y;                         \
        v.z = (DN) * (ACC.z + self.z) + b4.z;                         \
        v.w = (DN) * (ACC.w + self.w) + b4.w;                         \
        if (RELU) {                                                   \
            v.x = fmaxf(v.x, 0.f); v.y = fmaxf(v.y, 0.f);             \
            v.z = fmaxf(v.z, 0.f); v.w = fmaxf(v.w, 0.f);             \
        }                                                             \
        Q4[(size_t)(n0 + K) * 4 + hq] = v;                            \
    }
    FINISH(acc0, 0, d2.x)
    FINISH(acc1, 1, d2.y)
#undef FINISH
}

// ---------- 8. pool + fc ----------
__global__ __launch_bounds__(256) void k_pool_fc(const float* __restrict__ h2, const int* __restrict__ batch,
                                                 const float* __restrict__ Wfc, const float* __restrict__ bfc,
                                                 float* __restrict__ out) {
    int b = blockIdx.x;
    int lo = 0, hi = N_;
    while (lo < hi) { int m = (lo + hi) >> 1; if (batch[m] < b) lo = m + 1; else hi = m; }
    int start = lo;
    lo = start; hi = N_;
    while (lo < hi) { int m = (lo + hi) >> 1; if (batch[m] < b + 1) lo = m + 1; else hi = m; }
    int end = lo;

    int t = threadIdx.x;
    int h = t & 15, q = t >> 4;
    float acc = 0.f;
    for (int n = start + q; n < end; n += 16) acc += h2[(size_t)n * H_ + h];
    acc += __shfl_xor(acc, 16);
    acc += __shfl_xor(acc, 32);

    __shared__ float part[4][H_];
    __shared__ float pooled[H_];
    if ((t & 63) < 16) part[t >> 6][h] = acc;
    __syncthreads();
    if (t < H_) {
        float s2 = part[0][t] + part[1][t] + part[2][t] + part[3][t];
        pooled[t] = s2 / fmaxf((float)(end - start), 1.0f);
    }
    __syncthreads();
    if (t < C_) {
        float o = bfc[t];
#pragma unroll
        for (int hh = 0; hh < H_; ++hh) o += pooled[hh] * Wfc[hh * C_ + t];
        out[b * C_ + t] = o;
    }
}

extern "C" void kernel_launch(void* const* d_in, const int* in_sizes, int n_in,
                              void* d_out, int out_size, void* d_ws, size_t ws_size,
                              hipStream_t stream) {
    const float* x    = (const float*)d_in[0];
    const int*   ei   = (const int*)d_in[1];
    const int*   batch= (const int*)d_in[2];
    const float* W1   = (const float*)d_in[3];
    const float* b1   = (const float*)d_in[4];
    const float* W2   = (const float*)d_in[5];
    const float* b2   = (const float*)d_in[6];
    const float* Wfc  = (const float*)d_in[7];
    const float* bfc  = (const float*)d_in[8];
    float* out = (float*)d_out;

    const int* row = ei;          // sources
    const int* col = ei + E_;     // destinations

    size_t off = 0;
    auto alloc = [&](size_t bytes) -> void* {
        void* p = (char*)d_ws + off;
        off += (bytes + 255) & ~(size_t)255;
        return p;
    };
    // union: cnt1 (686*256*4 = 702 KB) dead after k_part1; off16 (7*N1*2 = 2.8 MB) written in k_part2
    char*           U        = (char*)alloc((size_t)NCH * N1 * 2);
    int*            cnt1     = (int*)U;
    unsigned short* off16    = (unsigned short*)U;
    int*            keyTotal = (int*)alloc((size_t)NKEY11 * 4);
    int*            ks686    = (int*)alloc((size_t)(NKEY11 + 1) * 4);
    int*            ks10     = (int*)alloc((size_t)(NKEY + 1) * 4);
    unsigned int*   edges    = (unsigned int*)alloc((size_t)E_ * 4);     // 25.6 MB (final sorted CSR)
    float*          dis      = (float*)alloc((size_t)N_ * 4);            // 0.8 MB
    float*          P        = (float*)alloc((size_t)N_ * H_ * 4);       // 12.8 MB
    float*          Q        = (float*)alloc((size_t)N_ * H_ * 4);       // 12.8 MB, contiguous after P
    // esrc (E_ words = 25.6 MB) aliases P∪Q: written by part1, consumed by part2, dead before gemm1 writes P.
    unsigned int*   esrc     = (unsigned int*)P;
    (void)ws_size; (void)in_sizes; (void)n_in; (void)out_size;

    const int gridN = (N_ + 255) / 256;

    // partition by 686 (chunk, dst>>11) keys (coarse -> full-line scatter chunks)
    k_count1  <<<NT, 1024, 0, stream>>>(row, col, cnt1);
    k_scan_col<<<NKEY11, 256, 0, stream>>>(cnt1, keyTotal);
    k_scan_top<<<1, 1024, 0, stream>>>(keyTotal, ks686, NKEY11);
    k_part1   <<<NT, 1024, 0, stream>>>(row, col, cnt1, ks686, esrc);
    // fine sort: 1372 blocks, each sorts one half-partition (dst bit 10 filter); emits ks10 + off16 + edges
    k_part2   <<<NKEY, 512, 0, stream>>>(esrc, ks686, ks10, off16, edges);

    // conv1 (dis fused into gemm1; pair x interleaved-quarter decomposition)
    k_gemm1s<<<G1B, 256, 0, stream>>>(x, W1, off16, ks10, dis, P);
    k_agg<1><<<AGGB, 256, 0, stream>>>((const float4*)P, edges, off16, ks10, dis, b1, (float4*)Q);
    // conv2
    k_gemm2s<<<gridN, 256, 0, stream>>>(Q, W2, dis, P);
    k_agg<0><<<AGGB, 256, 0, stream>>>((const float4*)P, edges, off16, ks10, dis, b2, (float4*)Q);

    k_pool_fc<<<B_, 256, 0, stream>>>(Q, batch, Wfc, bfc, out);
}